// Round 1
// baseline (449.705 us; speedup 1.0000x reference)
//
#include <hip/hip_runtime.h>
#include <stdint.h>

#define D_MODEL 1024
#define N_EXP   8
#define HIDDEN  2048
#define TOPK    2

#define BK   64
#define BM1  128
#define BN1  64
#define BM2  128
#define BN2  128

typedef short bf16x8 __attribute__((ext_vector_type(8)));
typedef float f32x4 __attribute__((ext_vector_type(4)));

__device__ __forceinline__ unsigned short f2bf(float f) {
    union { float f; unsigned u; } v; v.f = f;
    unsigned r = v.u + 0x7fffu + ((v.u >> 16) & 1u);
    return (unsigned short)(r >> 16);
}

__device__ __forceinline__ void gload_lds16(const void* g, void* l) {
    __builtin_amdgcn_global_load_lds(
        (const __attribute__((address_space(1))) void*)g,
        (__attribute__((address_space(3))) void*)l, 16, 0, 0);
}

// ---------------- convert x to bf16 ----------------
__global__ void k_cvt_x(const float* __restrict__ x, unsigned short* __restrict__ xb, int n8) {
    int i = blockIdx.x * blockDim.x + threadIdx.x;
    if (i >= n8) return;
    size_t base = (size_t)i * 8;
    float4 a = *(const float4*)(x + base);
    float4 b = *(const float4*)(x + base + 4);
    union { unsigned short us[8]; uint4 v; } pk;
    pk.us[0] = f2bf(a.x); pk.us[1] = f2bf(a.y); pk.us[2] = f2bf(a.z); pk.us[3] = f2bf(a.w);
    pk.us[4] = f2bf(b.x); pk.us[5] = f2bf(b.y); pk.us[6] = f2bf(b.z); pk.us[7] = f2bf(b.w);
    *(uint4*)(xb + base) = pk.v;
}

// ---------------- router: logits -> softmax -> top2 ----------------
__global__ void k_router(const float* __restrict__ x, const float* __restrict__ wr,
                         int* __restrict__ tok_e, float* __restrict__ tok_w,
                         int* __restrict__ counts, int T) {
    int t = blockIdx.x * (blockDim.x >> 6) + (threadIdx.x >> 6);
    int lane = threadIdx.x & 63;
    if (t >= T) return;
    const float* xr = x + (size_t)t * D_MODEL;
    float acc[N_EXP];
#pragma unroll
    for (int e = 0; e < N_EXP; ++e) acc[e] = 0.f;
    for (int d = lane; d < D_MODEL; d += 64) {
        float xv = xr[d];
        const float* w = wr + (size_t)d * N_EXP;
#pragma unroll
        for (int e = 0; e < N_EXP; ++e) acc[e] += xv * w[e];
    }
#pragma unroll
    for (int off = 32; off > 0; off >>= 1) {
#pragma unroll
        for (int e = 0; e < N_EXP; ++e) acc[e] += __shfl_down(acc[e], off, 64);
    }
    if (lane == 0) {
        float mx = acc[0];
#pragma unroll
        for (int e = 1; e < N_EXP; ++e) mx = fmaxf(mx, acc[e]);
        float p[N_EXP], den = 0.f;
#pragma unroll
        for (int e = 0; e < N_EXP; ++e) { p[e] = __expf(acc[e] - mx); den += p[e]; }
        float inv = 1.f / den;
        int e0 = 0; float v0 = acc[0];
#pragma unroll
        for (int e = 1; e < N_EXP; ++e) if (acc[e] > v0) { v0 = acc[e]; e0 = e; }
        int e1 = -1; float v1 = -1e30f;
#pragma unroll
        for (int e = 0; e < N_EXP; ++e) if (e != e0 && acc[e] > v1) { v1 = acc[e]; e1 = e; }
        tok_e[2 * t] = e0;     tok_w[2 * t] = p[e0] * inv;
        tok_e[2 * t + 1] = e1; tok_w[2 * t + 1] = p[e1] * inv;
        atomicAdd(&counts[e0], 1);
        atomicAdd(&counts[e1], 1);
    }
}

// ---------------- prefix scan of expert counts ----------------
__global__ void k_scan(const int* __restrict__ counts, int* __restrict__ offs, int* __restrict__ curs) {
    if (threadIdx.x == 0) {
        int s = 0;
        for (int e = 0; e < N_EXP; ++e) { offs[e] = s; curs[e] = s; s += counts[e]; }
        offs[N_EXP] = s;
    }
}

// ---------------- scatter tokens into expert-grouped rows ----------------
__global__ void k_scatter(const int* __restrict__ tok_e, const float* __restrict__ tok_w,
                          int* __restrict__ curs, int* __restrict__ row_token,
                          float* __restrict__ row_weight, int T) {
    int t = blockIdx.x * blockDim.x + threadIdx.x;
    if (t >= T) return;
#pragma unroll
    for (int k = 0; k < TOPK; ++k) {
        int e = tok_e[2 * t + k];
        int pos = atomicAdd(&curs[e], 1);
        row_token[pos] = t;
        row_weight[pos] = tok_w[2 * t + k];
    }
}

// ---------------- GEMM1: h = silu(x@w1) * (x@w3) * w_route  (grouped by expert) ----------------
__global__ __launch_bounds__(256) void k_gemm1(
    const unsigned short* __restrict__ xb,   // [T][D] bf16
    const float* __restrict__ w1,            // [E][D][H] f32
    const float* __restrict__ w3,
    const int* __restrict__ row_token,
    const float* __restrict__ row_weight,
    const int* __restrict__ offs,            // [E+1]
    unsigned short* __restrict__ h)          // [R][H] bf16
{
    __shared__ unsigned short A[BM1 * BK];
    __shared__ unsigned short B1[BN1 * BK];
    __shared__ unsigned short B3[BN1 * BK];

    const int e = blockIdx.z;
    const int off = offs[e];
    const int ne = offs[e + 1] - off;
    const int m0 = blockIdx.y * BM1;
    if (m0 >= ne) return;
    const int n0 = blockIdx.x * BN1;

    const int tid = threadIdx.x;
    const int lane = tid & 63, wid = tid >> 6;
    const int wm = wid >> 1, wn = wid & 1;

    // A staging: per-wave 4 global_load_lds instrs, pre-swizzled per-lane source
    const unsigned short* asrc[4];
    unsigned aoff[4];
#pragma unroll
    for (int q = 0; q < 4; ++q) {
        int i = wid * 4 + q;
        int c = i * 64 + lane;
        int m = c >> 3, kc = c & 7;
        int kcs = kc ^ (m & 7);
        int gm = m0 + m;
        int gmc = gm < ne ? gm : (ne - 1);
        int tok = row_token[off + gmc];
        asrc[q] = xb + (size_t)tok * D_MODEL + kcs * 8;
        aoff[q] = (unsigned)i * 512u;
    }

    const float* b1base = w1 + (size_t)e * D_MODEL * HIDDEN + n0;
    const float* b3base = w3 + (size_t)e * D_MODEL * HIDDEN + n0;

    f32x4 acc1[4][2], acc3[4][2];
    const f32x4 zf = {0.f, 0.f, 0.f, 0.f};
#pragma unroll
    for (int mi = 0; mi < 4; ++mi)
#pragma unroll
        for (int ni = 0; ni < 2; ++ni) { acc1[mi][ni] = zf; acc3[mi][ni] = zf; }

    for (int kt = 0; kt < D_MODEL / BK; ++kt) {
#pragma unroll
        for (int q = 0; q < 4; ++q)
            gload_lds16(asrc[q] + kt * BK, &A[aoff[q]]);
        // B1/B3 staging: reg-stage f32 -> bf16, XOR-swizzled LDS rows
#pragma unroll
        for (int s = 0; s < 2; ++s) {
            int u = tid + s * 256;
            int n = u & 63, kc = u >> 6;
            const float* p1 = b1base + (size_t)(kt * BK + kc * 8) * HIDDEN + n;
            const float* p3 = b3base + (size_t)(kt * BK + kc * 8) * HIDDEN + n;
            union { unsigned short us[8]; bf16x8 v; } pk1, pk3;
#pragma unroll
            for (int j = 0; j < 8; ++j) pk1.us[j] = f2bf(p1[(size_t)j * HIDDEN]);
#pragma unroll
            for (int j = 0; j < 8; ++j) pk3.us[j] = f2bf(p3[(size_t)j * HIDDEN]);
            int eo = n * BK + ((kc * 8) ^ ((n & 7) * 8));
            *(bf16x8*)(&B1[eo]) = pk1.v;
            *(bf16x8*)(&B3[eo]) = pk3.v;
        }
        __syncthreads();
#pragma unroll
        for (int kf = 0; kf < 2; ++kf) {
            bf16x8 a[4], b1f[2], b3f[2];
            int ke = kf * 32 + (lane >> 4) * 8;
#pragma unroll
            for (int mi = 0; mi < 4; ++mi) {
                int m = wm * 64 + mi * 16 + (lane & 15);
                a[mi] = *(const bf16x8*)(&A[m * BK + (ke ^ ((m & 7) * 8))]);
            }
#pragma unroll
            for (int ni = 0; ni < 2; ++ni) {
                int n = wn * 32 + ni * 16 + (lane & 15);
                int eo = n * BK + (ke ^ ((n & 7) * 8));
                b1f[ni] = *(const bf16x8*)(&B1[eo]);
                b3f[ni] = *(const bf16x8*)(&B3[eo]);
            }
#pragma unroll
            for (int mi = 0; mi < 4; ++mi)
#pragma unroll
                for (int ni = 0; ni < 2; ++ni) {
                    acc1[mi][ni] = __builtin_amdgcn_mfma_f32_16x16x32_bf16(a[mi], b1f[ni], acc1[mi][ni], 0, 0, 0);
                    acc3[mi][ni] = __builtin_amdgcn_mfma_f32_16x16x32_bf16(a[mi], b3f[ni], acc3[mi][ni], 0, 0, 0);
                }
        }
        __syncthreads();
    }

    // epilogue: h = silu(acc1)*acc3*w
#pragma unroll
    for (int mi = 0; mi < 4; ++mi) {
#pragma unroll
        for (int r = 0; r < 4; ++r) {
            int m = wm * 64 + mi * 16 + (lane >> 4) * 4 + r;
            int gm = m0 + m;
            if (gm < ne) {
                float wgt = row_weight[off + gm];
                size_t rowbase = (size_t)(off + gm) * HIDDEN + n0;
#pragma unroll
                for (int ni = 0; ni < 2; ++ni) {
                    float v1 = acc1[mi][ni][r], v3 = acc3[mi][ni][r];
                    float sv = v1 / (1.f + __expf(-v1));
                    int n = wn * 32 + ni * 16 + (lane & 15);
                    h[rowbase + n] = f2bf(sv * v3 * wgt);
                }
            }
        }
    }
}

// ---------------- GEMM2: out[token] += h @ w2 (grouped by expert) ----------------
__global__ __launch_bounds__(256) void k_gemm2(
    const unsigned short* __restrict__ h,   // [R][H] bf16
    const float* __restrict__ w2,           // [E][H][D] f32
    const int* __restrict__ row_token,
    const int* __restrict__ offs,
    float* __restrict__ out)
{
    __shared__ unsigned short A[BM2 * BK];
    __shared__ unsigned short B[BN2 * BK];

    const int e = blockIdx.z;
    const int off = offs[e];
    const int ne = offs[e + 1] - off;
    const int m0 = blockIdx.y * BM2;
    if (m0 >= ne) return;
    const int n0 = blockIdx.x * BN2;

    const int tid = threadIdx.x;
    const int lane = tid & 63, wid = tid >> 6;
    const int wm = wid >> 1, wn = wid & 1;

    const unsigned short* asrc[4];
    unsigned aoff[4];
#pragma unroll
    for (int q = 0; q < 4; ++q) {
        int i = wid * 4 + q;
        int c = i * 64 + lane;
        int m = c >> 3, kc = c & 7;
        int kcs = kc ^ (m & 7);
        int gm = m0 + m;
        int gmc = gm < ne ? gm : (ne - 1);
        asrc[q] = h + (size_t)(off + gmc) * HIDDEN + kcs * 8;
        aoff[q] = (unsigned)i * 512u;
    }

    const float* bbase = w2 + (size_t)e * HIDDEN * D_MODEL + n0;

    f32x4 acc[4][4];
    const f32x4 zf = {0.f, 0.f, 0.f, 0.f};
#pragma unroll
    for (int mi = 0; mi < 4; ++mi)
#pragma unroll
        for (int ni = 0; ni < 4; ++ni) acc[mi][ni] = zf;

    for (int kt = 0; kt < HIDDEN / BK; ++kt) {
#pragma unroll
        for (int q = 0; q < 4; ++q)
            gload_lds16(asrc[q] + kt * BK, &A[aoff[q]]);
#pragma unroll
        for (int s = 0; s < 4; ++s) {
            int u = tid + s * 256;
            int n = u & 127, kc = u >> 7;
            const float* p = bbase + (size_t)(kt * BK + kc * 8) * D_MODEL + n;
            union { unsigned short us[8]; bf16x8 v; } pk;
#pragma unroll
            for (int j = 0; j < 8; ++j) pk.us[j] = f2bf(p[(size_t)j * D_MODEL]);
            int eo = n * BK + ((kc * 8) ^ ((n & 7) * 8));
            *(bf16x8*)(&B[eo]) = pk.v;
        }
        __syncthreads();
#pragma unroll
        for (int kf = 0; kf < 2; ++kf) {
            bf16x8 a[4], b[4];
            int ke = kf * 32 + (lane >> 4) * 8;
#pragma unroll
            for (int mi = 0; mi < 4; ++mi) {
                int m = wm * 64 + mi * 16 + (lane & 15);
                a[mi] = *(const bf16x8*)(&A[m * BK + (ke ^ ((m & 7) * 8))]);
            }
#pragma unroll
            for (int ni = 0; ni < 4; ++ni) {
                int n = wn * 64 + ni * 16 + (lane & 15);
                b[ni] = *(const bf16x8*)(&B[n * BK + (ke ^ ((n & 7) * 8))]);
            }
#pragma unroll
            for (int mi = 0; mi < 4; ++mi)
#pragma unroll
                for (int ni = 0; ni < 4; ++ni)
                    acc[mi][ni] = __builtin_amdgcn_mfma_f32_16x16x32_bf16(a[mi], b[ni], acc[mi][ni], 0, 0, 0);
        }
        __syncthreads();
    }

    // epilogue: atomic combine into out[token]
#pragma unroll
    for (int mi = 0; mi < 4; ++mi) {
#pragma unroll
        for (int r = 0; r < 4; ++r) {
            int m = wm * 64 + mi * 16 + (lane >> 4) * 4 + r;
            int gm = m0 + m;
            if (gm < ne) {
                int tok = row_token[off + gm];
                float* orow = out + (size_t)tok * D_MODEL + n0;
#pragma unroll
                for (int ni = 0; ni < 4; ++ni) {
                    int n = wn * 64 + ni * 16 + (lane & 15);
                    __hip_atomic_fetch_add(&orow[n], acc[mi][ni][r],
                                           __ATOMIC_RELAXED, __HIP_MEMORY_SCOPE_AGENT);
                }
            }
        }
    }
}

extern "C" void kernel_launch(void* const* d_in, const int* in_sizes, int n_in,
                              void* d_out, int out_size, void* d_ws, size_t ws_size,
                              hipStream_t stream) {
    const float* x  = (const float*)d_in[0];
    const float* wr = (const float*)d_in[1];
    const float* w1 = (const float*)d_in[2];
    const float* w3 = (const float*)d_in[3];
    const float* w2 = (const float*)d_in[4];
    float* out = (float*)d_out;

    const int T = in_sizes[0] / D_MODEL;   // 4096
    const int R = T * TOPK;                // 8192

    char* ws = (char*)d_ws;
    size_t o = 0;
    unsigned short* xb = (unsigned short*)(ws + o); o += (size_t)T * D_MODEL * 2;
    unsigned short* h  = (unsigned short*)(ws + o); o += (size_t)R * HIDDEN * 2;
    int*   row_token  = (int*)(ws + o);   o += (size_t)R * 4;
    float* row_weight = (float*)(ws + o); o += (size_t)R * 4;
    int*   tok_e      = (int*)(ws + o);   o += (size_t)2 * T * 4;
    float* tok_w      = (float*)(ws + o); o += (size_t)2 * T * 4;
    int*   counts     = (int*)(ws + o);   o += 16 * 4;
    int*   offs       = (int*)(ws + o);   o += 16 * 4;
    int*   curs       = (int*)(ws + o);   o += 16 * 4;

    hipMemsetAsync(counts, 0, 16 * 4, stream);
    hipMemsetAsync(d_out, 0, (size_t)out_size * sizeof(float), stream);

    int n8 = T * D_MODEL / 8;
    k_cvt_x<<<(n8 + 255) / 256, 256, 0, stream>>>(x, xb, n8);
    k_router<<<(T + 3) / 4, 256, 0, stream>>>(x, wr, tok_e, tok_w, counts, T);
    k_scan<<<1, 64, 0, stream>>>(counts, offs, curs);
    k_scatter<<<(T + 255) / 256, 256, 0, stream>>>(tok_e, tok_w, curs, row_token, row_weight, T);

    dim3 g1(HIDDEN / BN1, (T + BM1 - 1) / BM1, N_EXP);
    k_gemm1<<<g1, 256, 0, stream>>>(xb, w1, w3, row_token, row_weight, offs, h);

    dim3 g2(D_MODEL / BN2, (T + BM2 - 1) / BM2, N_EXP);
    k_gemm2<<<g2, 256, 0, stream>>>(h, w2, row_token, offs, out);
}

// Round 2
// 398.084 us; speedup vs baseline: 1.1297x; 1.1297x over previous
//
#include <hip/hip_runtime.h>
#include <stdint.h>

#define D_MODEL 1024
#define N_EXP   8
#define HIDDEN  2048
#define TOPK    2

#define BK   64
#define BM1  128
#define BN1  64
#define BM2  128
#define BN2  128

typedef short bf16x8 __attribute__((ext_vector_type(8)));
typedef float f32x4 __attribute__((ext_vector_type(4)));

__device__ __forceinline__ unsigned short f2bf(float f) {
    union { float f; unsigned u; } v; v.f = f;
    unsigned r = v.u + 0x7fffu + ((v.u >> 16) & 1u);
    return (unsigned short)(r >> 16);
}

__device__ __forceinline__ void gload_lds16(const void* g, void* l) {
    __builtin_amdgcn_global_load_lds(
        (const __attribute__((address_space(1))) void*)g,
        (__attribute__((address_space(3))) void*)l, 16, 0, 0);
}

// ---------------- convert x to bf16 ----------------
__global__ void k_cvt_x(const float* __restrict__ x, unsigned short* __restrict__ xb, int n8) {
    int i = blockIdx.x * blockDim.x + threadIdx.x;
    if (i >= n8) return;
    size_t base = (size_t)i * 8;
    float4 a = *(const float4*)(x + base);
    float4 b = *(const float4*)(x + base + 4);
    union { unsigned short us[8]; uint4 v; } pk;
    pk.us[0] = f2bf(a.x); pk.us[1] = f2bf(a.y); pk.us[2] = f2bf(a.z); pk.us[3] = f2bf(a.w);
    pk.us[4] = f2bf(b.x); pk.us[5] = f2bf(b.y); pk.us[6] = f2bf(b.z); pk.us[7] = f2bf(b.w);
    *(uint4*)(xb + base) = pk.v;
}

// ---------------- convert + transpose weights: in [E][Rr][Cc] f32 -> out [E][Cc][Rr] bf16 ----------------
__global__ __launch_bounds__(256) void k_cvt_t(const float* __restrict__ in,
                                               unsigned short* __restrict__ out,
                                               int Rr, int Cc) {
    __shared__ unsigned short t[64][66];
    const size_t eb = (size_t)blockIdx.z * Rr * Cc;
    const int r0 = blockIdx.y * 64, c0 = blockIdx.x * 64;
    const int tid = threadIdx.x;
#pragma unroll
    for (int i = 0; i < 16; ++i) {
        int idx = i * 256 + tid;
        int r = idx >> 6, c = idx & 63;
        t[c][r] = f2bf(in[eb + (size_t)(r0 + r) * Cc + c0 + c]);
    }
    __syncthreads();
#pragma unroll
    for (int i = 0; i < 2; ++i) {
        int idx = i * 256 + tid;
        int hc = idx >> 3, d8 = (idx & 7) * 8;
        bf16x8 v = *(const bf16x8*)(&t[hc][d8]);
        *(bf16x8*)(&out[eb + (size_t)(c0 + hc) * Rr + r0 + d8]) = v;
    }
}

// ---------------- router: logits -> softmax -> top2 ----------------
__global__ void k_router(const float* __restrict__ x, const float* __restrict__ wr,
                         int* __restrict__ tok_e, float* __restrict__ tok_w,
                         int* __restrict__ counts, int T) {
    int t = blockIdx.x * (blockDim.x >> 6) + (threadIdx.x >> 6);
    int lane = threadIdx.x & 63;
    if (t >= T) return;
    const float* xr = x + (size_t)t * D_MODEL;
    float acc[N_EXP];
#pragma unroll
    for (int e = 0; e < N_EXP; ++e) acc[e] = 0.f;
    for (int d = lane; d < D_MODEL; d += 64) {
        float xv = xr[d];
        const float* w = wr + (size_t)d * N_EXP;
#pragma unroll
        for (int e = 0; e < N_EXP; ++e) acc[e] += xv * w[e];
    }
#pragma unroll
    for (int off = 32; off > 0; off >>= 1) {
#pragma unroll
        for (int e = 0; e < N_EXP; ++e) acc[e] += __shfl_down(acc[e], off, 64);
    }
    if (lane == 0) {
        float mx = acc[0];
#pragma unroll
        for (int e = 1; e < N_EXP; ++e) mx = fmaxf(mx, acc[e]);
        float p[N_EXP], den = 0.f;
#pragma unroll
        for (int e = 0; e < N_EXP; ++e) { p[e] = __expf(acc[e] - mx); den += p[e]; }
        float inv = 1.f / den;
        int e0 = 0; float v0 = acc[0];
#pragma unroll
        for (int e = 1; e < N_EXP; ++e) if (acc[e] > v0) { v0 = acc[e]; e0 = e; }
        int e1 = -1; float v1 = -1e30f;
#pragma unroll
        for (int e = 0; e < N_EXP; ++e) if (e != e0 && acc[e] > v1) { v1 = acc[e]; e1 = e; }
        tok_e[2 * t] = e0;     tok_w[2 * t] = p[e0] * inv;
        tok_e[2 * t + 1] = e1; tok_w[2 * t + 1] = p[e1] * inv;
        atomicAdd(&counts[e0], 1);
        atomicAdd(&counts[e1], 1);
    }
}

// ---------------- prefix scan of expert counts ----------------
__global__ void k_scan(const int* __restrict__ counts, int* __restrict__ offs, int* __restrict__ curs) {
    if (threadIdx.x == 0) {
        int s = 0;
        for (int e = 0; e < N_EXP; ++e) { offs[e] = s; curs[e] = s; s += counts[e]; }
        offs[N_EXP] = s;
    }
}

// ---------------- scatter tokens into expert-grouped rows ----------------
__global__ void k_scatter(const int* __restrict__ tok_e, const float* __restrict__ tok_w,
                          int* __restrict__ curs, int* __restrict__ row_token,
                          float* __restrict__ row_weight, int T) {
    int t = blockIdx.x * blockDim.x + threadIdx.x;
    if (t >= T) return;
#pragma unroll
    for (int k = 0; k < TOPK; ++k) {
        int e = tok_e[2 * t + k];
        int pos = atomicAdd(&curs[e], 1);
        row_token[pos] = t;
        row_weight[pos] = tok_w[2 * t + k];
    }
}

// ---------------- GEMM1: h = silu(x@w1) * (x@w3) * w_route  (grouped by expert) ----------------
__global__ __launch_bounds__(256) void k_gemm1(
    const unsigned short* __restrict__ xb,    // [T][D] bf16
    const unsigned short* __restrict__ w1t,   // [E][H][D] bf16 (transposed)
    const unsigned short* __restrict__ w3t,   // [E][H][D] bf16
    const int* __restrict__ row_token,
    const float* __restrict__ row_weight,
    const int* __restrict__ offs,             // [E+1]
    unsigned short* __restrict__ h)           // [R][H] bf16
{
    __shared__ unsigned short A[BM1 * BK];
    __shared__ unsigned short B1[BN1 * BK];
    __shared__ unsigned short B3[BN1 * BK];

    const int e = blockIdx.z;
    const int off = offs[e];
    const int ne = offs[e + 1] - off;
    const int m0 = blockIdx.y * BM1;
    if (m0 >= ne) return;
    const int n0 = blockIdx.x * BN1;

    const int tid = threadIdx.x;
    const int lane = tid & 63, wid = tid >> 6;
    const int wm = wid >> 1, wn = wid & 1;

    // A staging: 4 global_load_lds per thread, pre-swizzled per-lane source
    const unsigned short* asrc[4];
    unsigned aoff[4];
#pragma unroll
    for (int q = 0; q < 4; ++q) {
        int i = wid * 4 + q;
        int c = i * 64 + lane;
        int m = c >> 3, kc = c & 7;
        int kcs = kc ^ (m & 7);
        int gm = m0 + m;
        int gmc = gm < ne ? gm : (ne - 1);
        int tok = row_token[off + gmc];
        asrc[q] = xb + (size_t)tok * D_MODEL + kcs * 8;
        aoff[q] = (unsigned)i * 512u;
    }

    // B staging: 2 global_load_lds per thread per matrix, same pattern
    const unsigned short* b1src[2];
    const unsigned short* b3src[2];
    unsigned boff[2];
#pragma unroll
    for (int q = 0; q < 2; ++q) {
        int i = wid * 2 + q;             // 0..7
        int n = i * 8 + (lane >> 3);     // 0..63
        int kc = lane & 7;
        int kcs = kc ^ (n & 7);
        b1src[q] = w1t + ((size_t)e * HIDDEN + n0 + n) * D_MODEL + kcs * 8;
        b3src[q] = w3t + ((size_t)e * HIDDEN + n0 + n) * D_MODEL + kcs * 8;
        boff[q] = (unsigned)i * 512u;
    }

    f32x4 acc1[4][2], acc3[4][2];
    const f32x4 zf = {0.f, 0.f, 0.f, 0.f};
#pragma unroll
    for (int mi = 0; mi < 4; ++mi)
#pragma unroll
        for (int ni = 0; ni < 2; ++ni) { acc1[mi][ni] = zf; acc3[mi][ni] = zf; }

    for (int kt = 0; kt < D_MODEL / BK; ++kt) {
#pragma unroll
        for (int q = 0; q < 4; ++q)
            gload_lds16(asrc[q] + kt * BK, &A[aoff[q]]);
#pragma unroll
        for (int q = 0; q < 2; ++q) {
            gload_lds16(b1src[q] + kt * BK, &B1[boff[q]]);
            gload_lds16(b3src[q] + kt * BK, &B3[boff[q]]);
        }
        __syncthreads();
#pragma unroll
        for (int kf = 0; kf < 2; ++kf) {
            bf16x8 a[4], b1f[2], b3f[2];
            int ke = kf * 32 + (lane >> 4) * 8;
#pragma unroll
            for (int mi = 0; mi < 4; ++mi) {
                int m = wm * 64 + mi * 16 + (lane & 15);
                a[mi] = *(const bf16x8*)(&A[m * BK + (ke ^ ((m & 7) * 8))]);
            }
#pragma unroll
            for (int ni = 0; ni < 2; ++ni) {
                int n = wn * 32 + ni * 16 + (lane & 15);
                int eo = n * BK + (ke ^ ((n & 7) * 8));
                b1f[ni] = *(const bf16x8*)(&B1[eo]);
                b3f[ni] = *(const bf16x8*)(&B3[eo]);
            }
#pragma unroll
            for (int mi = 0; mi < 4; ++mi)
#pragma unroll
                for (int ni = 0; ni < 2; ++ni) {
                    acc1[mi][ni] = __builtin_amdgcn_mfma_f32_16x16x32_bf16(a[mi], b1f[ni], acc1[mi][ni], 0, 0, 0);
                    acc3[mi][ni] = __builtin_amdgcn_mfma_f32_16x16x32_bf16(a[mi], b3f[ni], acc3[mi][ni], 0, 0, 0);
                }
        }
        __syncthreads();
    }

    // epilogue: h = silu(acc1)*acc3*w
#pragma unroll
    for (int mi = 0; mi < 4; ++mi) {
#pragma unroll
        for (int r = 0; r < 4; ++r) {
            int m = wm * 64 + mi * 16 + (lane >> 4) * 4 + r;
            int gm = m0 + m;
            if (gm < ne) {
                float wgt = row_weight[off + gm];
                size_t rowbase = (size_t)(off + gm) * HIDDEN + n0;
#pragma unroll
                for (int ni = 0; ni < 2; ++ni) {
                    float v1 = acc1[mi][ni][r], v3 = acc3[mi][ni][r];
                    float sv = v1 / (1.f + __expf(-v1));
                    int n = wn * 32 + ni * 16 + (lane & 15);
                    h[rowbase + n] = f2bf(sv * v3 * wgt);
                }
            }
        }
    }
}

// ---------------- GEMM2: out[token] += h @ w2 (grouped by expert) ----------------
__global__ __launch_bounds__(256) void k_gemm2(
    const unsigned short* __restrict__ h,    // [R][H] bf16
    const unsigned short* __restrict__ w2t,  // [E][D][H] bf16 (transposed)
    const int* __restrict__ row_token,
    const int* __restrict__ offs,
    float* __restrict__ out)
{
    __shared__ unsigned short A[BM2 * BK];
    __shared__ unsigned short B[BN2 * BK];

    const int e = blockIdx.z;
    const int off = offs[e];
    const int ne = offs[e + 1] - off;
    const int m0 = blockIdx.y * BM2;
    if (m0 >= ne) return;
    const int n0 = blockIdx.x * BN2;

    const int tid = threadIdx.x;
    const int lane = tid & 63, wid = tid >> 6;
    const int wm = wid >> 1, wn = wid & 1;

    const unsigned short* asrc[4];
    unsigned aoff[4];
#pragma unroll
    for (int q = 0; q < 4; ++q) {
        int i = wid * 4 + q;
        int c = i * 64 + lane;
        int m = c >> 3, kc = c & 7;
        int kcs = kc ^ (m & 7);
        int gm = m0 + m;
        int gmc = gm < ne ? gm : (ne - 1);
        asrc[q] = h + (size_t)(off + gmc) * HIDDEN + kcs * 8;
        aoff[q] = (unsigned)i * 512u;
    }

    const unsigned short* bsrc[4];
    unsigned boff[4];
#pragma unroll
    for (int q = 0; q < 4; ++q) {
        int i = wid * 4 + q;             // 0..15
        int n = i * 8 + (lane >> 3);     // 0..127
        int kc = lane & 7;
        int kcs = kc ^ (n & 7);
        bsrc[q] = w2t + ((size_t)e * D_MODEL + n0 + n) * HIDDEN + kcs * 8;
        boff[q] = (unsigned)i * 512u;
    }

    f32x4 acc[4][4];
    const f32x4 zf = {0.f, 0.f, 0.f, 0.f};
#pragma unroll
    for (int mi = 0; mi < 4; ++mi)
#pragma unroll
        for (int ni = 0; ni < 4; ++ni) acc[mi][ni] = zf;

    for (int kt = 0; kt < HIDDEN / BK; ++kt) {
#pragma unroll
        for (int q = 0; q < 4; ++q)
            gload_lds16(asrc[q] + kt * BK, &A[aoff[q]]);
#pragma unroll
        for (int q = 0; q < 4; ++q)
            gload_lds16(bsrc[q] + kt * BK, &B[boff[q]]);
        __syncthreads();
#pragma unroll
        for (int kf = 0; kf < 2; ++kf) {
            bf16x8 a[4], b[4];
            int ke = kf * 32 + (lane >> 4) * 8;
#pragma unroll
            for (int mi = 0; mi < 4; ++mi) {
                int m = wm * 64 + mi * 16 + (lane & 15);
                a[mi] = *(const bf16x8*)(&A[m * BK + (ke ^ ((m & 7) * 8))]);
            }
#pragma unroll
            for (int ni = 0; ni < 4; ++ni) {
                int n = wn * 64 + ni * 16 + (lane & 15);
                b[ni] = *(const bf16x8*)(&B[n * BK + (ke ^ ((n & 7) * 8))]);
            }
#pragma unroll
            for (int mi = 0; mi < 4; ++mi)
#pragma unroll
                for (int ni = 0; ni < 4; ++ni)
                    acc[mi][ni] = __builtin_amdgcn_mfma_f32_16x16x32_bf16(a[mi], b[ni], acc[mi][ni], 0, 0, 0);
        }
        __syncthreads();
    }

    // epilogue: atomic combine into out[token]
#pragma unroll
    for (int mi = 0; mi < 4; ++mi) {
#pragma unroll
        for (int r = 0; r < 4; ++r) {
            int m = wm * 64 + mi * 16 + (lane >> 4) * 4 + r;
            int gm = m0 + m;
            if (gm < ne) {
                int tok = row_token[off + gm];
                float* orow = out + (size_t)tok * D_MODEL + n0;
#pragma unroll
                for (int ni = 0; ni < 4; ++ni) {
                    int n = wn * 64 + ni * 16 + (lane & 15);
                    __hip_atomic_fetch_add(&orow[n], acc[mi][ni][r],
                                           __ATOMIC_RELAXED, __HIP_MEMORY_SCOPE_AGENT);
                }
            }
        }
    }
}

extern "C" void kernel_launch(void* const* d_in, const int* in_sizes, int n_in,
                              void* d_out, int out_size, void* d_ws, size_t ws_size,
                              hipStream_t stream) {
    const float* x  = (const float*)d_in[0];
    const float* wr = (const float*)d_in[1];
    const float* w1 = (const float*)d_in[2];
    const float* w3 = (const float*)d_in[3];
    const float* w2 = (const float*)d_in[4];
    float* out = (float*)d_out;

    const int T = in_sizes[0] / D_MODEL;   // 4096
    const int R = T * TOPK;                // 8192

    char* ws = (char*)d_ws;
    size_t o = 0;
    unsigned short* xb  = (unsigned short*)(ws + o); o += (size_t)T * D_MODEL * 2;
    unsigned short* h   = (unsigned short*)(ws + o); o += (size_t)R * HIDDEN * 2;
    unsigned short* w1t = (unsigned short*)(ws + o); o += (size_t)N_EXP * D_MODEL * HIDDEN * 2;
    unsigned short* w3t = (unsigned short*)(ws + o); o += (size_t)N_EXP * D_MODEL * HIDDEN * 2;
    unsigned short* w2t = (unsigned short*)(ws + o); o += (size_t)N_EXP * HIDDEN * D_MODEL * 2;
    int*   row_token  = (int*)(ws + o);   o += (size_t)R * 4;
    float* row_weight = (float*)(ws + o); o += (size_t)R * 4;
    int*   tok_e      = (int*)(ws + o);   o += (size_t)2 * T * 4;
    float* tok_w      = (float*)(ws + o); o += (size_t)2 * T * 4;
    int*   counts     = (int*)(ws + o);   o += 16 * 4;
    int*   offs       = (int*)(ws + o);   o += 16 * 4;
    int*   curs       = (int*)(ws + o);   o += 16 * 4;

    hipMemsetAsync(counts, 0, 16 * 4, stream);
    hipMemsetAsync(d_out, 0, (size_t)out_size * sizeof(float), stream);

    int n8 = T * D_MODEL / 8;
    k_cvt_x<<<(n8 + 255) / 256, 256, 0, stream>>>(x, xb, n8);

    // weight convert+transpose: w1,w3: [D][H] -> [H][D]; w2: [H][D] -> [D][H]
    dim3 gt13(HIDDEN / 64, D_MODEL / 64, N_EXP);
    k_cvt_t<<<gt13, 256, 0, stream>>>(w1, w1t, D_MODEL, HIDDEN);
    k_cvt_t<<<gt13, 256, 0, stream>>>(w3, w3t, D_MODEL, HIDDEN);
    dim3 gt2(D_MODEL / 64, HIDDEN / 64, N_EXP);
    k_cvt_t<<<gt2, 256, 0, stream>>>(w2, w2t, HIDDEN, D_MODEL);

    k_router<<<(T + 3) / 4, 256, 0, stream>>>(x, wr, tok_e, tok_w, counts, T);
    k_scan<<<1, 64, 0, stream>>>(counts, offs, curs);
    k_scatter<<<(T + 255) / 256, 256, 0, stream>>>(tok_e, tok_w, curs, row_token, row_weight, T);

    dim3 g1(HIDDEN / BN1, (T + BM1 - 1) / BM1, N_EXP);
    k_gemm1<<<g1, 256, 0, stream>>>(xb, w1t, w3t, row_token, row_weight, offs, h);

    dim3 g2(D_MODEL / BN2, (T + BM2 - 1) / BM2, N_EXP);
    k_gemm2<<<g2, 256, 0, stream>>>(h, w2t, row_token, offs, out);
}